// Round 8
// baseline (464.511 us; speedup 1.0000x reference)
//
#include <hip/hip_runtime.h>
#include <hip/hip_bf16.h>

// Problem constants (from reference)
#define N_NODES 50000
#define N_REL   8
#define DIM     128      // IN_DIM == HID == 128
#define N_EDGES 800000
#define N_TRIP  100000
#define NSEG    (N_NODES * N_REL)   // 400000
#define NBUCKET 196                 // ceil(50000/256) dst buckets
#define CAP     6144                // slack slots per bucket (mean 4082)

typedef __attribute__((ext_vector_type(8))) short bf16x8;
typedef __attribute__((ext_vector_type(4))) float f32x4;

static __device__ __forceinline__ unsigned short f2b(float f) {
    __hip_bfloat16 h = __float2bfloat16(f);
    return *reinterpret_cast<unsigned short*>(&h);
}
static __device__ __forceinline__ float blo(unsigned int u) {
    return __uint_as_float(u << 16);
}
static __device__ __forceinline__ float bhi(unsigned int u) {
    return __uint_as_float(u & 0xffff0000u);
}
// XOR-swizzled LDS offset (units: shorts): chunk c of row n -> slot (c ^ (n&7))
static __device__ __forceinline__ int lds_off(int row, int chunk) {
    return (row * 16 + (chunk ^ (row & 7))) * 8;
}

// ---------------------------------------------------------------------------
// bucket_scatter: bin edges by dst>>8 into fixed-capacity slack regions.
// packed word: src[0:16) | rel[16:19) | dstLow[19:27)   (R0's proven kernel)
__global__ __launch_bounds__(256) void bucket_scatter(
        const int* __restrict__ edge_index,
        const int* __restrict__ edge_type,
        int* __restrict__ gcnt,
        unsigned int* __restrict__ slack) {
    __shared__ int hist[NBUCKET];
    __shared__ int cur[NBUCKET];
    int tid = threadIdx.x;
    for (int i = tid; i < NBUCKET; i += 256) hist[i] = 0;
    __syncthreads();
    int base = blockIdx.x * 4096;
    unsigned int w[16];
    int bk[16];
    #pragma unroll
    for (int i = 0; i < 16; ++i) {
        int e = base + i * 256 + tid;
        if (e < N_EDGES) {
            int src = edge_index[e];
            int dst = edge_index[N_EDGES + e];
            int r = edge_type[e];
            w[i] = (unsigned int)src | ((unsigned int)r << 16) |
                   ((unsigned int)(dst & 255) << 19);
            bk[i] = dst >> 8;
            atomicAdd(&hist[bk[i]], 1);
        } else {
            bk[i] = -1;
        }
    }
    __syncthreads();
    for (int i = tid; i < NBUCKET; i += 256)
        cur[i] = atomicAdd(&gcnt[i], hist[i]);
    __syncthreads();
    #pragma unroll
    for (int i = 0; i < 16; ++i) {
        if (bk[i] >= 0) {
            int p = atomicAdd(&cur[bk[i]], 1);
            if (p < CAP) slack[(size_t)bk[i] * CAP + p] = w[i];
        }
    }
}

// ---------------------------------------------------------------------------
// bucket_scan: exclusive scan of 196 bucket counts; also set sentinel.
__global__ void bucket_scan(const int* __restrict__ gcnt,
                            int* __restrict__ gbase,
                            int* __restrict__ offsets) {
    __shared__ int sh[256];
    int t = threadIdx.x;
    int v = (t < NBUCKET) ? gcnt[t] : 0;
    sh[t] = v;
    __syncthreads();
    #pragma unroll
    for (int off = 1; off < 256; off <<= 1) {
        int x = (t >= off) ? sh[t - off] : 0;
        __syncthreads();
        sh[t] += x;
        __syncthreads();
    }
    if (t < NBUCKET) gbase[t] = sh[t] - v;
    if (t == 0) offsets[NSEG] = N_EDGES;
}

// ---------------------------------------------------------------------------
// bucket_sort: one block per bucket. LDS counting sort over 2048 local segs
// (dstLow*8+rel). Writes sorted_pack (src|rel<<16|dstLow<<19) and offsets
// (dst-major). R0's proven kernel.
__global__ __launch_bounds__(256) void bucket_sort(
        const unsigned int* __restrict__ slack,
        const int* __restrict__ gcnt,
        const int* __restrict__ gbase,
        unsigned int* __restrict__ sorted_pack,
        int* __restrict__ offsets) {
    __shared__ unsigned int ebuf[CAP];   // 24 KB
    __shared__ unsigned int obuf[CAP];   // 24 KB
    __shared__ int hist[2048];           // 8 KB (later reused as cursor)
    __shared__ int excl[2048];           // 8 KB
    __shared__ int sh[256];
    int b = blockIdx.x, t = threadIdx.x;
    int n = gcnt[b]; if (n > CAP) n = CAP;
    int bb = gbase[b];
    for (int i = t; i < n; i += 256) ebuf[i] = slack[(size_t)b * CAP + i];
    for (int i = t; i < 2048; i += 256) hist[i] = 0;
    __syncthreads();
    for (int i = t; i < n; i += 256) {
        unsigned int w = ebuf[i];
        int seg = (int)((w >> 19) << 3) | (int)((w >> 16) & 7u);
        atomicAdd(&hist[seg], 1);
    }
    __syncthreads();
    // blocked exclusive scan over 2048: thread t owns [t*8, t*8+8)
    int c[8];
    int s = 0;
    #pragma unroll
    for (int j = 0; j < 8; ++j) { c[j] = hist[t * 8 + j]; s += c[j]; }
    sh[t] = s;
    __syncthreads();
    #pragma unroll
    for (int off = 1; off < 256; off <<= 1) {
        int x = (t >= off) ? sh[t - off] : 0;
        __syncthreads();
        sh[t] += x;
        __syncthreads();
    }
    int ex = sh[t] - s;
    #pragma unroll
    for (int j = 0; j < 8; ++j) { excl[t * 8 + j] = ex; ex += c[j]; }
    __syncthreads();
    #pragma unroll
    for (int j = 0; j < 8; ++j) hist[t * 8 + j] = excl[t * 8 + j];  // cursor
    __syncthreads();
    for (int i = t; i < n; i += 256) {
        unsigned int w = ebuf[i];
        int seg = (int)((w >> 19) << 3) | (int)((w >> 16) & 7u);
        int p = atomicAdd(&hist[seg], 1);
        obuf[p] = w;
    }
    __syncthreads();
    for (int i = t; i < n; i += 256) sorted_pack[bb + i] = obuf[i];
    int segbase = b * 2048;
    #pragma unroll
    for (int j = 0; j < 8; ++j) {
        int gseg = segbase + t * 8 + j;
        if (gseg < NSEG) offsets[gseg] = bb + excl[t * 8 + j];
    }
}

// ---------------------------------------------------------------------------
// cvt_emb: fp32 -> bf16, 2 elems/thread (packed)
__global__ void cvt_emb_kernel(const float* __restrict__ src,
                               unsigned short* __restrict__ dst) {
    int i = blockIdx.x * blockDim.x + threadIdx.x;
    const int npair = N_NODES * DIM / 2;
    if (i >= npair) return;
    float2 v = ((const float2*)src)[i];
    unsigned int p = (unsigned int)f2b(v.x) | ((unsigned int)f2b(v.y) << 16);
    ((unsigned int*)dst)[i] = p;
}

// ---------------------------------------------------------------------------
// cvt_w2: Wt2[s][n][k] bf16 for both layers; s=0 -> root, s>=1 -> W_{s-1}.
__global__ void cvt_w2_kernel(const float* __restrict__ root0,
                              const float* __restrict__ W0,
                              const float* __restrict__ root1,
                              const float* __restrict__ W1,
                              unsigned short* __restrict__ Wt2a,
                              unsigned short* __restrict__ Wt2b) {
    int s = blockIdx.x;        // 0..8
    int n = blockIdx.y;        // 0..127
    int k = threadIdx.x;       // 0..127
    const float* root = blockIdx.z ? root1 : root0;
    const float* W    = blockIdx.z ? W1 : W0;
    unsigned short* Wt2 = blockIdx.z ? Wt2b : Wt2a;
    float v = (s == 0) ? root[k * 128 + n]
                       : W[((size_t)(s - 1) * 128 + k) * 128 + n];
    Wt2[((size_t)s * 128 + n) * 128 + k] = f2b(v);
}

// ---------------------------------------------------------------------------
// aggregate_mean: R0's aggregate_out structure VERBATIM (one wave per dst,
// 4 dsts per 256-thr block, NO LDS, NO barriers, free VGPRs) but gathering
// raw h rows (12.8 MB, L2/L3-hot) and writing per-rel bf16 MEAN rows to
// Ym[8][N][128] (102 MB streaming, coalesced 256B stores). Flush-on-rel-
// change; empty rels zero-filled. Barrier-free => no convoy tax (R7 lesson).
#define FLUSH()                                                                \
    do {                                                                       \
        float inv_ = __builtin_amdgcn_rcpf((float)cnt);                        \
        Ym32[((size_t)curr * N_NODES + dst) * 64 + lane] =                     \
            (unsigned int)f2b(a0 * inv_) | ((unsigned int)f2b(a1 * inv_) << 16);\
        flushed |= 1u << curr;                                                 \
    } while (0)

#define CONSUME(w_, v_)                                                        \
    do {                                                                       \
        int r_ = (int)(((w_) >> 16) & 7u);                                     \
        float x0_ = blo(v_), x1_ = bhi(v_);                                    \
        if (r_ != curr) {                                                      \
            if (curr >= 0) FLUSH();                                            \
            curr = r_; a0 = x0_; a1 = x1_; cnt = 1;                            \
        } else { a0 += x0_; a1 += x1_; ++cnt; }                                 \
    } while (0)

__global__ __launch_bounds__(256) void aggregate_mean(
        const unsigned short* __restrict__ hb,    // N x 128 bf16
        const int* __restrict__ offsets,          // NSEG+1, dst-major
        const unsigned int* __restrict__ spack,   // src|rel<<16|dstLow<<19
        unsigned short* __restrict__ Ym) {        // 8 x N x 128 bf16
    int dst = blockIdx.x * 4 + (threadIdx.x >> 6);
    if (dst >= N_NODES) return;
    int lane = threadIdx.x & 63;
    const unsigned int* hb32 = (const unsigned int*)hb;
    unsigned int* Ym32 = (unsigned int*)Ym;

    int beg = offsets[dst * 8];
    int end = offsets[dst * 8 + 8];

    float a0 = 0.f, a1 = 0.f;
    int curr = -1, cnt = 0;
    unsigned int flushed = 0;
    for (int base = beg; base < end; base += 64) {
        int m = end - base; if (m > 64) m = 64;
        unsigned int pk = 0;
        if (lane < m) pk = spack[base + lane];
        int j = 0;
        for (; j + 8 <= m; j += 8) {              // UNGUARDED: 8 loads in flight
            unsigned int pp[8], vv[8];
            #pragma unroll
            for (int q = 0; q < 8; ++q)
                pp[q] = (unsigned int)__shfl((int)pk, j + q, 64);
            #pragma unroll
            for (int q = 0; q < 8; ++q)
                vv[q] = hb32[(size_t)(pp[q] & 0xffffu) * 64 + lane];
            #pragma unroll
            for (int q = 0; q < 8; ++q) CONSUME(pp[q], vv[q]);
        }
        for (; j < m; ++j) {                      // scalar tail
            unsigned int p1 = (unsigned int)__shfl((int)pk, j, 64);
            unsigned int v1 = hb32[(size_t)(p1 & 0xffffu) * 64 + lane];
            CONSUME(p1, v1);
        }
    }
    if (curr >= 0) FLUSH();
    // zero-fill rels with no edges (mean = 0)
    #pragma unroll
    for (int r = 0; r < 8; ++r)
        if (!((flushed >> r) & 1u))
            Ym32[((size_t)r * N_NODES + dst) * 64 + lane] = 0u;
}

// ---------------------------------------------------------------------------
// gemm9r: R0's measured gemm9_bn32 structure, but the 9 slot-results SUM
// into one accumulator: h_out[n] = relu(bias + sum_s A_s[n] @ B_s), with
// A_0 = h (root) and A_s = Ym[s-1] (rel means). A-frags re-loaded per slot
// (sequential 16B, L3-served); Bs = 8 KB swizzled stage per slot. Writes
// collapse 112.5 MB -> 12.5 MB vs R0.
__global__ __launch_bounds__(256) void gemm9r(
        const unsigned short* __restrict__ hb,    // N x 128 bf16
        const unsigned short* __restrict__ Ym,    // 8 x N x 128 bf16
        const unsigned short* __restrict__ Wt2,   // 9 x 128(n) x 128(k) bf16
        const float* __restrict__ bias,           // 128
        unsigned short* __restrict__ hout) {      // N x 128 bf16
    __shared__ unsigned short Bs[32 * 16 * 8];    // 8 KB swizzled

    int tid = threadIdx.x;
    int wave = tid >> 6, lane = tid & 63;
    int wm = wave & 1, wn = wave >> 1;            // 32-row half / 16-col half
    int quad = lane >> 4, l16 = lane & 15;
    int row0 = blockIdx.x * 64;
    int col0 = blockIdx.y * 32;

    // this wave's A rows (two 16-row fragments)
    int grow2[2];
    #pragma unroll
    for (int i = 0; i < 2; ++i) {
        int g = row0 + wm * 32 + i * 16 + l16;
        grow2[i] = (g < N_NODES) ? g : (N_NODES - 1);
    }

    f32x4 acc[2];
    acc[0] = (f32x4){0.f, 0.f, 0.f, 0.f};
    acc[1] = (f32x4){0.f, 0.f, 0.f, 0.f};

    for (int s = 0; s < 9; ++s) {
        __syncthreads();   // previous slot's Bs reads done
        {
            // stage 32 n-rows x 128 k: thread -> row tid>>3, chunks (tid&7)*2..+1
            int n = tid >> 3, c0 = (tid & 7) * 2;
            const unsigned short* gp = Wt2 + ((size_t)s * 128 + col0 + n) * 128 + c0 * 8;
            #pragma unroll
            for (int q = 0; q < 2; ++q)
                *(bf16x8*)&Bs[lds_off(n, c0 + q)] = *(const bf16x8*)(gp + q * 8);
        }
        __syncthreads();

        const unsigned short* Asrc = (s == 0)
            ? hb : (Ym + (size_t)(s - 1) * N_NODES * DIM);
        #pragma unroll
        for (int kk = 0; kk < 4; ++kk) {
            int chunk = kk * 4 + quad;
            bf16x8 bfr = *(const bf16x8*)&Bs[lds_off(wn * 16 + l16, chunk)];
            #pragma unroll
            for (int i = 0; i < 2; ++i) {
                bf16x8 afr = *(const bf16x8*)(Asrc + (size_t)grow2[i] * DIM
                                              + kk * 32 + quad * 8);
                acc[i] = __builtin_amdgcn_mfma_f32_16x16x32_bf16(
                    afr, bfr, acc[i], 0, 0, 0);
            }
        }
    }

    // epilogue: bias + relu + bf16 store
    // C/D layout: col = lane&15, row = (lane>>4)*4 + reg
    int gc = col0 + wn * 16 + l16;
    float bv = bias[gc];
    #pragma unroll
    for (int i = 0; i < 2; ++i) {
        int gr0 = row0 + wm * 32 + i * 16 + quad * 4;
        #pragma unroll
        for (int r = 0; r < 4; ++r) {
            int grow = gr0 + r;
            if (grow < N_NODES)
                hout[(size_t)grow * DIM + gc] = f2b(fmaxf(acc[i][r] + bv, 0.f));
        }
    }
}

// ---------------------------------------------------------------------------
// score: out[t] = sum_d h[head,d]*rel_emb[rel,d]*h[tail,d]  (h in bf16)
__global__ void score_kernel(const unsigned short* __restrict__ hb,
                             const float* __restrict__ rel_emb,
                             const int* __restrict__ head,
                             const int* __restrict__ rel,
                             const int* __restrict__ tail,
                             float* __restrict__ out) {
    int t = blockIdx.x * 4 + (threadIdx.x >> 6);
    if (t >= N_TRIP) return;
    int lane = threadIdx.x & 63;
    unsigned int ph = ((const unsigned int*)(hb + (size_t)head[t] * DIM))[lane];
    unsigned int pt = ((const unsigned int*)(hb + (size_t)tail[t] * DIM))[lane];
    float2 rr = ((const float2*)(rel_emb + (size_t)rel[t] * DIM))[lane];
    float s = blo(ph) * rr.x * blo(pt) + bhi(ph) * rr.y * bhi(pt);
    #pragma unroll
    for (int off = 32; off; off >>= 1) s += __shfl_xor(s, off, 64);
    if (lane == 0) out[t] = s;
}

// ---------------------------------------------------------------------------
extern "C" void kernel_launch(void* const* d_in, const int* in_sizes, int n_in,
                              void* d_out, int out_size, void* d_ws, size_t ws_size,
                              hipStream_t stream) {
    const float* emb     = (const float*)d_in[0];
    const float* W0      = (const float*)d_in[1];
    const float* root0   = (const float*)d_in[2];
    const float* b0      = (const float*)d_in[3];
    const float* W1      = (const float*)d_in[4];
    const float* root1   = (const float*)d_in[5];
    const float* b1      = (const float*)d_in[6];
    const float* rel_emb = (const float*)d_in[7];
    const int* edge_index = (const int*)d_in[8];
    const int* edge_type  = (const int*)d_in[9];
    const int* head_idx   = (const int*)d_in[10];
    const int* rel_idx    = (const int*)d_in[11];
    const int* tail_idx   = (const int*)d_in[12];
    float* out = (float*)d_out;

    // workspace layout (~151 MB, all disjoint, largest first for alignment):
    char* p = (char*)d_ws;
    size_t ym_bytes  = (size_t)8 * N_NODES * DIM * sizeof(unsigned short);   // 102.4 MB
    size_t hb_bytes  = (size_t)N_NODES * DIM * sizeof(unsigned short);       // 12.8 MB
    size_t wt2_bytes = (size_t)9 * 128 * 128 * sizeof(unsigned short);       // 294912 B
    unsigned short* Ym   = (unsigned short*)p; p += ym_bytes;
    unsigned short* embb = (unsigned short*)p; p += hb_bytes;
    unsigned short* h1b  = (unsigned short*)p; p += hb_bytes;
    unsigned short* h2b  = (unsigned short*)p; p += hb_bytes;
    unsigned short* Wt2a = (unsigned short*)p; p += wt2_bytes;
    unsigned short* Wt2b = (unsigned short*)p; p += wt2_bytes;
    unsigned int* spack = (unsigned int*)p;   p += (size_t)N_EDGES * sizeof(unsigned int);
    unsigned int* slack = (unsigned int*)p;   p += (size_t)NBUCKET * CAP * sizeof(unsigned int);
    int* gcnt  = (int*)p;  p += (size_t)NBUCKET * sizeof(int);
    int* gbase = (int*)p;  p += (size_t)NBUCKET * sizeof(int);
    int* offsets = (int*)p;
    (void)ws_size; (void)in_sizes; (void)n_in; (void)out_size;

    dim3 blk256(256);

    // ---- 2-pass bucket sort of edges by (dst, rel), dst-major ----
    hipMemsetAsync(gcnt, 0, (size_t)NBUCKET * sizeof(int), stream);
    bucket_scatter<<<(N_EDGES + 4095) / 4096, blk256, 0, stream>>>(edge_index, edge_type,
                                                                   gcnt, slack);
    bucket_scan<<<1, 256, 0, stream>>>(gcnt, gbase, offsets);
    bucket_sort<<<NBUCKET, blk256, 0, stream>>>(slack, gcnt, gbase, spack, offsets);

    // ---- precision conversions ----
    cvt_emb_kernel<<<(N_NODES * DIM / 2 + 255) / 256, blk256, 0, stream>>>(emb, embb);
    cvt_w2_kernel<<<dim3(9, 128, 2), 128, 0, stream>>>(root0, W0, root1, W1, Wt2a, Wt2b);

    int agrid = (N_NODES + 3) / 4;                 // 12500 blocks, 1 wave/dst
    dim3 ggrid((N_NODES + 63) / 64, 4);            // 782 x 4 = 3128 blocks

    // ---- layer 0: aggregate means (barrier-free) then fused-sum GEMM ----
    aggregate_mean<<<agrid, blk256, 0, stream>>>(embb, offsets, spack, Ym);
    gemm9r<<<ggrid, blk256, 0, stream>>>(embb, Ym, Wt2a, b0, h1b);

    // ---- layer 1 ----
    aggregate_mean<<<agrid, blk256, 0, stream>>>(h1b, offsets, spack, Ym);
    gemm9r<<<ggrid, blk256, 0, stream>>>(h1b, Ym, Wt2b, b1, h2b);

    // ---- score ----
    score_kernel<<<(N_TRIP + 3) / 4, blk256, 0, stream>>>(h2b, rel_emb, head_idx, rel_idx,
                                                          tail_idx, out);
}

// Round 9
// 376.720 us; speedup vs baseline: 1.2330x; 1.2330x over previous
//
#include <hip/hip_runtime.h>
#include <hip/hip_bf16.h>

// Problem constants (from reference)
#define N_NODES 50000
#define N_REL   8
#define DIM     128      // IN_DIM == HID == 128
#define N_EDGES 800000
#define N_TRIP  100000
#define NSEG    (N_NODES * N_REL)   // 400000
#define NBUCKET 196                 // ceil(50000/256) dst buckets
#define CAP     6144                // slack slots per bucket (mean 4082)

typedef __attribute__((ext_vector_type(8))) short bf16x8;
typedef __attribute__((ext_vector_type(4))) float f32x4;

static __device__ __forceinline__ unsigned short f2b(float f) {
    __hip_bfloat16 h = __float2bfloat16(f);
    return *reinterpret_cast<unsigned short*>(&h);
}
static __device__ __forceinline__ float blo(unsigned int u) {
    return __uint_as_float(u << 16);
}
static __device__ __forceinline__ float bhi(unsigned int u) {
    return __uint_as_float(u & 0xffff0000u);
}
// XOR-swizzled LDS offset (units: shorts): chunk c of row n -> slot (c ^ (n&7))
static __device__ __forceinline__ int lds_off(int row, int chunk) {
    return (row * 16 + (chunk ^ (row & 7))) * 8;
}

// ---------------------------------------------------------------------------
// bucket_scatter: bin edges by dst>>8 into fixed-capacity slack regions.
// packed word: src[0:16) | rel[16:19) | dstLow[19:27)   (R0's proven kernel)
__global__ __launch_bounds__(256) void bucket_scatter(
        const int* __restrict__ edge_index,
        const int* __restrict__ edge_type,
        int* __restrict__ gcnt,
        unsigned int* __restrict__ slack) {
    __shared__ int hist[NBUCKET];
    __shared__ int cur[NBUCKET];
    int tid = threadIdx.x;
    for (int i = tid; i < NBUCKET; i += 256) hist[i] = 0;
    __syncthreads();
    int base = blockIdx.x * 4096;
    unsigned int w[16];
    int bk[16];
    #pragma unroll
    for (int i = 0; i < 16; ++i) {
        int e = base + i * 256 + tid;
        if (e < N_EDGES) {
            int src = edge_index[e];
            int dst = edge_index[N_EDGES + e];
            int r = edge_type[e];
            w[i] = (unsigned int)src | ((unsigned int)r << 16) |
                   ((unsigned int)(dst & 255) << 19);
            bk[i] = dst >> 8;
            atomicAdd(&hist[bk[i]], 1);
        } else {
            bk[i] = -1;
        }
    }
    __syncthreads();
    for (int i = tid; i < NBUCKET; i += 256)
        cur[i] = atomicAdd(&gcnt[i], hist[i]);
    __syncthreads();
    #pragma unroll
    for (int i = 0; i < 16; ++i) {
        if (bk[i] >= 0) {
            int p = atomicAdd(&cur[bk[i]], 1);
            if (p < CAP) slack[(size_t)bk[i] * CAP + p] = w[i];
        }
    }
}

// ---------------------------------------------------------------------------
// bucket_scan: exclusive scan of 196 bucket counts; also set sentinel.
__global__ void bucket_scan(const int* __restrict__ gcnt,
                            int* __restrict__ gbase,
                            int* __restrict__ offsets) {
    __shared__ int sh[256];
    int t = threadIdx.x;
    int v = (t < NBUCKET) ? gcnt[t] : 0;
    sh[t] = v;
    __syncthreads();
    #pragma unroll
    for (int off = 1; off < 256; off <<= 1) {
        int x = (t >= off) ? sh[t - off] : 0;
        __syncthreads();
        sh[t] += x;
        __syncthreads();
    }
    if (t < NBUCKET) gbase[t] = sh[t] - v;
    if (t == 0) offsets[NSEG] = N_EDGES;
}

// ---------------------------------------------------------------------------
// bucket_sort: one block per bucket. LDS counting sort over 2048 local segs
// (dstLow*8+rel). Writes sorted_pack (src|rel<<16|dstLow<<19) and offsets
// (dst-major). R0's proven kernel.
__global__ __launch_bounds__(256) void bucket_sort(
        const unsigned int* __restrict__ slack,
        const int* __restrict__ gcnt,
        const int* __restrict__ gbase,
        unsigned int* __restrict__ sorted_pack,
        int* __restrict__ offsets) {
    __shared__ unsigned int ebuf[CAP];   // 24 KB
    __shared__ unsigned int obuf[CAP];   // 24 KB
    __shared__ int hist[2048];           // 8 KB (later reused as cursor)
    __shared__ int excl[2048];           // 8 KB
    __shared__ int sh[256];
    int b = blockIdx.x, t = threadIdx.x;
    int n = gcnt[b]; if (n > CAP) n = CAP;
    int bb = gbase[b];
    for (int i = t; i < n; i += 256) ebuf[i] = slack[(size_t)b * CAP + i];
    for (int i = t; i < 2048; i += 256) hist[i] = 0;
    __syncthreads();
    for (int i = t; i < n; i += 256) {
        unsigned int w = ebuf[i];
        int seg = (int)((w >> 19) << 3) | (int)((w >> 16) & 7u);
        atomicAdd(&hist[seg], 1);
    }
    __syncthreads();
    // blocked exclusive scan over 2048: thread t owns [t*8, t*8+8)
    int c[8];
    int s = 0;
    #pragma unroll
    for (int j = 0; j < 8; ++j) { c[j] = hist[t * 8 + j]; s += c[j]; }
    sh[t] = s;
    __syncthreads();
    #pragma unroll
    for (int off = 1; off < 256; off <<= 1) {
        int x = (t >= off) ? sh[t - off] : 0;
        __syncthreads();
        sh[t] += x;
        __syncthreads();
    }
    int ex = sh[t] - s;
    #pragma unroll
    for (int j = 0; j < 8; ++j) { excl[t * 8 + j] = ex; ex += c[j]; }
    __syncthreads();
    #pragma unroll
    for (int j = 0; j < 8; ++j) hist[t * 8 + j] = excl[t * 8 + j];  // cursor
    __syncthreads();
    for (int i = t; i < n; i += 256) {
        unsigned int w = ebuf[i];
        int seg = (int)((w >> 19) << 3) | (int)((w >> 16) & 7u);
        int p = atomicAdd(&hist[seg], 1);
        obuf[p] = w;
    }
    __syncthreads();
    for (int i = t; i < n; i += 256) sorted_pack[bb + i] = obuf[i];
    int segbase = b * 2048;
    #pragma unroll
    for (int j = 0; j < 8; ++j) {
        int gseg = segbase + t * 8 + j;
        if (gseg < NSEG) offsets[gseg] = bb + excl[t * 8 + j];
    }
}

// ---------------------------------------------------------------------------
// cvt_emb: fp32 -> bf16, 2 elems/thread (packed)
__global__ void cvt_emb_kernel(const float* __restrict__ src,
                               unsigned short* __restrict__ dst) {
    int i = blockIdx.x * blockDim.x + threadIdx.x;
    const int npair = N_NODES * DIM / 2;
    if (i >= npair) return;
    float2 v = ((const float2*)src)[i];
    unsigned int p = (unsigned int)f2b(v.x) | ((unsigned int)f2b(v.y) << 16);
    ((unsigned int*)dst)[i] = p;
}

// ---------------------------------------------------------------------------
// cvt_w2: Wt2[s][n][k] bf16 for both layers; s=0 -> root, s>=1 -> W_{s-1}.
__global__ void cvt_w2_kernel(const float* __restrict__ root0,
                              const float* __restrict__ W0,
                              const float* __restrict__ root1,
                              const float* __restrict__ W1,
                              unsigned short* __restrict__ Wt2a,
                              unsigned short* __restrict__ Wt2b) {
    int s = blockIdx.x;        // 0..8
    int n = blockIdx.y;        // 0..127
    int k = threadIdx.x;       // 0..127
    const float* root = blockIdx.z ? root1 : root0;
    const float* W    = blockIdx.z ? W1 : W0;
    unsigned short* Wt2 = blockIdx.z ? Wt2b : Wt2a;
    float v = (s == 0) ? root[k * 128 + n]
                       : W[((size_t)(s - 1) * 128 + k) * 128 + n];
    Wt2[((size_t)s * 128 + n) * 128 + k] = f2b(v);
}

// ---------------------------------------------------------------------------
// aggregate_mean: R0's aggregate_out structure VERBATIM (one wave per dst,
// 4 dsts per 256-thr block, NO LDS, NO barriers) gathering raw h rows
// (12.8 MB, L2/L3-hot) and writing per-rel bf16 MEAN rows to Ym[8][N][128].
#define FLUSH()                                                                \
    do {                                                                       \
        float inv_ = __builtin_amdgcn_rcpf((float)cnt);                        \
        Ym32[((size_t)curr * N_NODES + dst) * 64 + lane] =                     \
            (unsigned int)f2b(a0 * inv_) | ((unsigned int)f2b(a1 * inv_) << 16);\
        flushed |= 1u << curr;                                                 \
    } while (0)

#define CONSUME(w_, v_)                                                        \
    do {                                                                       \
        int r_ = (int)(((w_) >> 16) & 7u);                                     \
        float x0_ = blo(v_), x1_ = bhi(v_);                                    \
        if (r_ != curr) {                                                      \
            if (curr >= 0) FLUSH();                                            \
            curr = r_; a0 = x0_; a1 = x1_; cnt = 1;                            \
        } else { a0 += x0_; a1 += x1_; ++cnt; }                                 \
    } while (0)

__global__ __launch_bounds__(256) void aggregate_mean(
        const unsigned short* __restrict__ hb,    // N x 128 bf16
        const int* __restrict__ offsets,          // NSEG+1, dst-major
        const unsigned int* __restrict__ spack,   // src|rel<<16|dstLow<<19
        unsigned short* __restrict__ Ym) {        // 8 x N x 128 bf16
    int dst = blockIdx.x * 4 + (threadIdx.x >> 6);
    if (dst >= N_NODES) return;
    int lane = threadIdx.x & 63;
    const unsigned int* hb32 = (const unsigned int*)hb;
    unsigned int* Ym32 = (unsigned int*)Ym;

    int beg = offsets[dst * 8];
    int end = offsets[dst * 8 + 8];

    float a0 = 0.f, a1 = 0.f;
    int curr = -1, cnt = 0;
    unsigned int flushed = 0;
    for (int base = beg; base < end; base += 64) {
        int m = end - base; if (m > 64) m = 64;
        unsigned int pk = 0;
        if (lane < m) pk = spack[base + lane];
        int j = 0;
        for (; j + 8 <= m; j += 8) {              // UNGUARDED: 8 loads in flight
            unsigned int pp[8], vv[8];
            #pragma unroll
            for (int q = 0; q < 8; ++q)
                pp[q] = (unsigned int)__shfl((int)pk, j + q, 64);
            #pragma unroll
            for (int q = 0; q < 8; ++q)
                vv[q] = hb32[(size_t)(pp[q] & 0xffffu) * 64 + lane];
            #pragma unroll
            for (int q = 0; q < 8; ++q) CONSUME(pp[q], vv[q]);
        }
        for (; j < m; ++j) {                      // scalar tail
            unsigned int p1 = (unsigned int)__shfl((int)pk, j, 64);
            unsigned int v1 = hb32[(size_t)(p1 & 0xffffu) * 64 + lane];
            CONSUME(p1, v1);
        }
    }
    if (curr >= 0) FLUSH();
    // zero-fill rels with no edges (mean = 0)
    #pragma unroll
    for (int r = 0; r < 8; ++r)
        if (!((flushed >> r) & 1u))
            Ym32[((size_t)r * N_NODES + dst) * 64 + lane] = 0u;
}

// ---------------------------------------------------------------------------
// gemm9r v2: h_out[n] = relu(bias + sum_s A_s[n] @ B_s), A_0 = h, A_s =
// Ym[s-1]. Fixes R8's 227 MB over-fetch: (1) grid flipped to (4, 782) so the
// 4 col-blocks sharing a row-tile are CO-RESIDENT (A fetched from HBM once,
// 3 L2/L3 hits); (2) wave layout 16 rows x 32 cols: each A-frag feeds 2
// MFMAs and no two waves load the same A rows (zero intra-block redundancy).
__global__ __launch_bounds__(256) void gemm9r(
        const unsigned short* __restrict__ hb,    // N x 128 bf16
        const unsigned short* __restrict__ Ym,    // 8 x N x 128 bf16
        const unsigned short* __restrict__ Wt2,   // 9 x 128(n) x 128(k) bf16
        const float* __restrict__ bias,           // 128
        unsigned short* __restrict__ hout) {      // N x 128 bf16
    __shared__ unsigned short Bs[32 * 16 * 8];    // 8 KB swizzled

    int tid = threadIdx.x;
    int wave = tid >> 6, lane = tid & 63;
    int quad = lane >> 4, l16 = lane & 15;
    int col0 = blockIdx.x * 32;                   // 0..3  (fastest index)
    int row0 = blockIdx.y * 64;                   // 0..781

    // wave owns rows [row0 + wave*16, +16), all 32 cols
    int grow = row0 + wave * 16 + l16;
    if (grow >= N_NODES) grow = N_NODES - 1;

    f32x4 acc[2];
    acc[0] = (f32x4){0.f, 0.f, 0.f, 0.f};
    acc[1] = (f32x4){0.f, 0.f, 0.f, 0.f};

    for (int s = 0; s < 9; ++s) {
        __syncthreads();   // previous slot's Bs reads done
        {
            // stage 32 n-rows x 128 k: thread -> row tid>>3, chunks (tid&7)*2..+1
            int n = tid >> 3, c0 = (tid & 7) * 2;
            const unsigned short* gp = Wt2 + ((size_t)s * 128 + col0 + n) * 128 + c0 * 8;
            #pragma unroll
            for (int q = 0; q < 2; ++q)
                *(bf16x8*)&Bs[lds_off(n, c0 + q)] = *(const bf16x8*)(gp + q * 8);
        }
        __syncthreads();

        const unsigned short* Ap = ((s == 0)
            ? hb : (Ym + (size_t)(s - 1) * N_NODES * DIM)) + (size_t)grow * DIM;
        #pragma unroll
        for (int kk = 0; kk < 4; ++kk) {
            bf16x8 afr = *(const bf16x8*)(Ap + kk * 32 + quad * 8);
            int chunk = kk * 4 + quad;
            bf16x8 bfr0 = *(const bf16x8*)&Bs[lds_off(l16, chunk)];
            bf16x8 bfr1 = *(const bf16x8*)&Bs[lds_off(16 + l16, chunk)];
            acc[0] = __builtin_amdgcn_mfma_f32_16x16x32_bf16(afr, bfr0, acc[0], 0, 0, 0);
            acc[1] = __builtin_amdgcn_mfma_f32_16x16x32_bf16(afr, bfr1, acc[1], 0, 0, 0);
        }
    }

    // epilogue: bias + relu + bf16 store
    // C/D layout: col = lane&15, row = (lane>>4)*4 + reg
    #pragma unroll
    for (int ni = 0; ni < 2; ++ni) {
        int gc = col0 + ni * 16 + l16;
        float bv = bias[gc];
        int gr0 = row0 + wave * 16 + quad * 4;
        #pragma unroll
        for (int r = 0; r < 4; ++r) {
            int gr = gr0 + r;
            if (gr < N_NODES)
                hout[(size_t)gr * DIM + gc] = f2b(fmaxf(acc[ni][r] + bv, 0.f));
        }
    }
}

// ---------------------------------------------------------------------------
// score: out[t] = sum_d h[head,d]*rel_emb[rel,d]*h[tail,d]  (h in bf16)
__global__ void score_kernel(const unsigned short* __restrict__ hb,
                             const float* __restrict__ rel_emb,
                             const int* __restrict__ head,
                             const int* __restrict__ rel,
                             const int* __restrict__ tail,
                             float* __restrict__ out) {
    int t = blockIdx.x * 4 + (threadIdx.x >> 6);
    if (t >= N_TRIP) return;
    int lane = threadIdx.x & 63;
    unsigned int ph = ((const unsigned int*)(hb + (size_t)head[t] * DIM))[lane];
    unsigned int pt = ((const unsigned int*)(hb + (size_t)tail[t] * DIM))[lane];
    float2 rr = ((const float2*)(rel_emb + (size_t)rel[t] * DIM))[lane];
    float s = blo(ph) * rr.x * blo(pt) + bhi(ph) * rr.y * bhi(pt);
    #pragma unroll
    for (int off = 32; off; off >>= 1) s += __shfl_xor(s, off, 64);
    if (lane == 0) out[t] = s;
}

// ---------------------------------------------------------------------------
extern "C" void kernel_launch(void* const* d_in, const int* in_sizes, int n_in,
                              void* d_out, int out_size, void* d_ws, size_t ws_size,
                              hipStream_t stream) {
    const float* emb     = (const float*)d_in[0];
    const float* W0      = (const float*)d_in[1];
    const float* root0   = (const float*)d_in[2];
    const float* b0      = (const float*)d_in[3];
    const float* W1      = (const float*)d_in[4];
    const float* root1   = (const float*)d_in[5];
    const float* b1      = (const float*)d_in[6];
    const float* rel_emb = (const float*)d_in[7];
    const int* edge_index = (const int*)d_in[8];
    const int* edge_type  = (const int*)d_in[9];
    const int* head_idx   = (const int*)d_in[10];
    const int* rel_idx    = (const int*)d_in[11];
    const int* tail_idx   = (const int*)d_in[12];
    float* out = (float*)d_out;

    // workspace layout (~151 MB, all disjoint, largest first for alignment):
    char* p = (char*)d_ws;
    size_t ym_bytes  = (size_t)8 * N_NODES * DIM * sizeof(unsigned short);   // 102.4 MB
    size_t hb_bytes  = (size_t)N_NODES * DIM * sizeof(unsigned short);       // 12.8 MB
    size_t wt2_bytes = (size_t)9 * 128 * 128 * sizeof(unsigned short);       // 294912 B
    unsigned short* Ym   = (unsigned short*)p; p += ym_bytes;
    unsigned short* embb = (unsigned short*)p; p += hb_bytes;
    unsigned short* h1b  = (unsigned short*)p; p += hb_bytes;
    unsigned short* h2b  = (unsigned short*)p; p += hb_bytes;
    unsigned short* Wt2a = (unsigned short*)p; p += wt2_bytes;
    unsigned short* Wt2b = (unsigned short*)p; p += wt2_bytes;
    unsigned int* spack = (unsigned int*)p;   p += (size_t)N_EDGES * sizeof(unsigned int);
    unsigned int* slack = (unsigned int*)p;   p += (size_t)NBUCKET * CAP * sizeof(unsigned int);
    int* gcnt  = (int*)p;  p += (size_t)NBUCKET * sizeof(int);
    int* gbase = (int*)p;  p += (size_t)NBUCKET * sizeof(int);
    int* offsets = (int*)p;
    (void)ws_size; (void)in_sizes; (void)n_in; (void)out_size;

    dim3 blk256(256);

    // ---- 2-pass bucket sort of edges by (dst, rel), dst-major ----
    hipMemsetAsync(gcnt, 0, (size_t)NBUCKET * sizeof(int), stream);
    bucket_scatter<<<(N_EDGES + 4095) / 4096, blk256, 0, stream>>>(edge_index, edge_type,
                                                                   gcnt, slack);
    bucket_scan<<<1, 256, 0, stream>>>(gcnt, gbase, offsets);
    bucket_sort<<<NBUCKET, blk256, 0, stream>>>(slack, gcnt, gbase, spack, offsets);

    // ---- precision conversions ----
    cvt_emb_kernel<<<(N_NODES * DIM / 2 + 255) / 256, blk256, 0, stream>>>(emb, embb);
    cvt_w2_kernel<<<dim3(9, 128, 2), 128, 0, stream>>>(root0, W0, root1, W1, Wt2a, Wt2b);

    int agrid = (N_NODES + 3) / 4;                 // 12500 blocks, 1 wave/dst
    dim3 ggrid(4, (N_NODES + 63) / 64);            // col-fastest: A-sharing blocks co-resident

    // ---- layer 0: aggregate means (barrier-free) then fused-sum GEMM ----
    aggregate_mean<<<agrid, blk256, 0, stream>>>(embb, offsets, spack, Ym);
    gemm9r<<<ggrid, blk256, 0, stream>>>(embb, Ym, Wt2a, b0, h1b);

    // ---- layer 1 ----
    aggregate_mean<<<agrid, blk256, 0, stream>>>(h1b, offsets, spack, Ym);
    gemm9r<<<ggrid, blk256, 0, stream>>>(h1b, Ym, Wt2b, b1, h2b);

    // ---- score ----
    score_kernel<<<(N_TRIP + 3) / 4, blk256, 0, stream>>>(h2b, rel_emb, head_idx, rel_idx,
                                                          tail_idx, out);
}